// Round 1
// baseline (66.013 us; speedup 1.0000x reference)
//
#include <hip/hip_runtime.h>

#define NB 4096
#define TT 256
#define SS 5
#define DD 32
#define NT 4
#define TPAD 264   // t-dim stride for xsT (bank-friendly, 16B-aligned rows)

// XOR-swizzle on t (bits 3..4, keyed by d bits 2..3) to break staging-write conflicts
#define XCOL(d, t) ((t) ^ (((((d) >> 2)) & 3) << 3))

__device__ __forceinline__ float frcp(float x) { return __builtin_amdgcn_rcpf(x); }
__device__ __forceinline__ float sigmoidf_(float v) { return frcp(1.f + __expf(-v)); }

__global__ void __launch_bounds__(256)
mem_net_kernel(const float* __restrict__ x,
               const float* __restrict__ q,
               const float* __restrict__ keys,
               const float* __restrict__ Wu,
               const float* __restrict__ bu,
               const int*   __restrict__ lens,
               const int*   __restrict__ labels,
               const int*   __restrict__ qlab,
               float*       __restrict__ out)
{
    __shared__ __align__(16) float xsT[DD][TPAD];   // x_b transposed: [d][t]
    __shared__ __align__(16) float kT[DD][NT][8];   // keys: [d][type][s(pad8)]
    __shared__ __align__(16) float wuS[DD][DD];     // Wu: [k][n]
    __shared__ __align__(16) float buS[DD];
    __shared__ __align__(16) float qS[DD];
    __shared__ __align__(16) float attnS[SS][TT];   // a_t[s], then w_t[s] in place
    __shared__ __align__(16) float cS[TT];
    __shared__ __align__(16) float rS[8];
    __shared__ __align__(16) float redS[32][33];

    const int b   = blockIdx.x;
    const int tid = threadIdx.x;
    const int len = lens[b];
    const int ql  = qlab[b];

    // ---------------- Phase A: stage ----------------
    {
        const float* xb = x + (size_t)b * (TT * DD);
        const int nchunk = len * (DD / 4);          // valid float4 chunks
        #pragma unroll
        for (int it = 0; it < (TT * DD / 4) / 256; ++it) {   // 8 iterations
            const int j  = tid + it * 256;
            const int t  = j >> 3;
            const int c4 = (j & 7) << 2;
            float4 v = make_float4(0.f, 0.f, 0.f, 0.f);
            if (j < nchunk) v = *reinterpret_cast<const float4*>(xb + (size_t)j * 4);
            xsT[c4 + 0][XCOL(c4 + 0, t)] = v.x;
            xsT[c4 + 1][XCOL(c4 + 1, t)] = v.y;
            xsT[c4 + 2][XCOL(c4 + 2, t)] = v.z;
            xsT[c4 + 3][XCOL(c4 + 3, t)] = v.w;
        }
        for (int i = tid; i < NT * SS * DD; i += 256) {
            const int ty = i / (SS * DD);
            const int s  = (i / DD) % SS;
            const int d  = i % DD;
            kT[d][ty][s] = keys[i];                 // keys flat: ((ty*SS)+s)*DD+d
        }
        for (int i = tid; i < DD * DD; i += 256) wuS[i >> 5][i & 31] = Wu[i];
        if (tid < DD) { buS[tid] = bu[tid]; qS[tid] = q[(size_t)b * DD + tid]; }
    }
    __syncthreads();

    // ---------------- Phase B: attention softmax per (b,t) ----------------
    {
        const int t = tid;
        float a0 = 0.f, a1 = 0.f, a2 = 0.f, a3 = 0.f, a4 = 0.f;
        if (t < len) {
            const int lab = (t < len - 1) ? labels[(size_t)b * TT + t] : 0;
            float z0 = 0.f, z1 = 0.f, z2 = 0.f, z3 = 0.f, z4 = 0.f;
            #pragma unroll
            for (int d = 0; d < DD; ++d) {
                const float xv = xsT[d][XCOL(d, t)];
                const float* kp = &kT[d][lab][0];
                z0 += xv * kp[0]; z1 += xv * kp[1]; z2 += xv * kp[2];
                z3 += xv * kp[3]; z4 += xv * kp[4];
            }
            const float m = fmaxf(fmaxf(fmaxf(z0, z1), fmaxf(z2, z3)), z4);
            const float e0 = __expf(z0 - m), e1 = __expf(z1 - m), e2 = __expf(z2 - m),
                        e3 = __expf(z3 - m), e4 = __expf(z4 - m);
            const float inv = frcp(e0 + e1 + e2 + e3 + e4);
            a0 = e0 * inv; a1 = e1 * inv; a2 = e2 * inv; a3 = e3 * inv; a4 = e4 * inv;
        }
        attnS[0][t] = a0; attnS[1][t] = a1; attnS[2][t] = a2;
        attnS[3][t] = a3; attnS[4][t] = a4;
    }
    __syncthreads();

    // ---------------- Phase C: r_attn + suffix-product scans -> w, then c_t ----
    {
        const int wave = tid >> 6;
        const int lane = tid & 63;
        if (wave == 0) {
            // r_attn = softmax_s(q . keys[ql][s]) computed cooperatively on 32-lane halves
            const int d = lane & 31;
            float p0 = qS[d] * kT[d][ql][0];
            float p1 = qS[d] * kT[d][ql][1];
            float p2 = qS[d] * kT[d][ql][2];
            float p3 = qS[d] * kT[d][ql][3];
            float p4 = qS[d] * kT[d][ql][4];
            #pragma unroll
            for (int m = 16; m >= 1; m >>= 1) {
                p0 += __shfl_xor(p0, m); p1 += __shfl_xor(p1, m); p2 += __shfl_xor(p2, m);
                p3 += __shfl_xor(p3, m); p4 += __shfl_xor(p4, m);
            }
            const float mm = fmaxf(fmaxf(fmaxf(p0, p1), fmaxf(p2, p3)), p4);
            const float e0 = __expf(p0 - mm), e1 = __expf(p1 - mm), e2 = __expf(p2 - mm),
                        e3 = __expf(p3 - mm), e4 = __expf(p4 - mm);
            const float inv = frcp(e0 + e1 + e2 + e3 + e4);
            if (lane == 0) {
                rS[0] = e0 * inv; rS[1] = e1 * inv; rS[2] = e2 * inv;
                rS[3] = e3 * inv; rS[4] = e4 * inv;
            }
        }
        // suffix-product scans: wave w handles s = w (wave 0 also s = 4)
        for (int s = wave; s < SS; s += 4) {
            float4 av = *reinterpret_cast<float4*>(&attnS[s][lane << 2]);
            const float om0 = 1.f - av.x, om1 = 1.f - av.y, om2 = 1.f - av.z, om3 = 1.f - av.w;
            float p = om0 * om1 * om2 * om3;
            #pragma unroll
            for (int off = 1; off < 64; off <<= 1) {
                const float o = __shfl_down(p, off);
                p = (lane + off < 64) ? p * o : p;
            }
            float suf = __shfl_down(p, 1);          // exclusive suffix of chunk products
            if (lane == 63) suf = 1.f;
            const float w3 = av.w * suf; suf *= om3;
            const float w2 = av.z * suf; suf *= om2;
            const float w1 = av.y * suf; suf *= om1;
            const float w0 = av.x * suf;
            *reinterpret_cast<float4*>(&attnS[s][lane << 2]) = make_float4(w0, w1, w2, w3);
        }
    }
    __syncthreads();
    {
        const float c = rS[0] * attnS[0][tid] + rS[1] * attnS[1][tid] +
                        rS[2] * attnS[2][tid] + rS[3] * attnS[3][tid] +
                        rS[4] * attnS[4][tid];
        cS[tid] = c;
    }
    __syncthreads();

    // ---------------- Phase D: U = sigmoid(X@Wu + bu), pref = sum_t c_t*U_t ----
    {
        const int cg = tid & 7;                     // cols 4*cg .. 4*cg+3
        const int rg = tid >> 3;                    // rows 8*rg .. 8*rg+7
        float acc[8][4];
        #pragma unroll
        for (int i = 0; i < 8; ++i)
            #pragma unroll
            for (int j = 0; j < 4; ++j) acc[i][j] = 0.f;

        float part0 = 0.f, part1 = 0.f, part2 = 0.f, part3 = 0.f;
        if (rg * 8 < len) {
            #pragma unroll
            for (int k = 0; k < DD; ++k) {
                const int rgs = (rg ^ ((k >> 2) & 3)) << 3;    // undo XCOL swizzle
                const float4 a01 = *reinterpret_cast<float4*>(&xsT[k][rgs]);
                const float4 a23 = *reinterpret_cast<float4*>(&xsT[k][rgs + 4]);
                const float4 wv  = *reinterpret_cast<float4*>(&wuS[k][cg << 2]);
                const float av[8] = {a01.x, a01.y, a01.z, a01.w,
                                     a23.x, a23.y, a23.z, a23.w};
                #pragma unroll
                for (int i = 0; i < 8; ++i) {
                    acc[i][0] += av[i] * wv.x;
                    acc[i][1] += av[i] * wv.y;
                    acc[i][2] += av[i] * wv.z;
                    acc[i][3] += av[i] * wv.w;
                }
            }
            const float b0 = buS[(cg << 2) + 0], b1 = buS[(cg << 2) + 1];
            const float b2 = buS[(cg << 2) + 2], b3 = buS[(cg << 2) + 3];
            #pragma unroll
            for (int i = 0; i < 8; ++i) {
                const float c = cS[rg * 8 + i];     // 0 for t >= len
                part0 += c * sigmoidf_(acc[i][0] + b0);
                part1 += c * sigmoidf_(acc[i][1] + b1);
                part2 += c * sigmoidf_(acc[i][2] + b2);
                part3 += c * sigmoidf_(acc[i][3] + b3);
            }
        }
        redS[rg][(cg << 2) + 0] = part0;
        redS[rg][(cg << 2) + 1] = part1;
        redS[rg][(cg << 2) + 2] = part2;
        redS[rg][(cg << 2) + 3] = part3;
    }
    __syncthreads();
    if (tid < 32) {
        float s = 0.f;
        #pragma unroll
        for (int r = 0; r < 32; ++r) s += redS[r][tid];
        out[(size_t)b * DD + tid] = s;
    }
}

extern "C" void kernel_launch(void* const* d_in, const int* in_sizes, int n_in,
                              void* d_out, int out_size, void* d_ws, size_t ws_size,
                              hipStream_t stream) {
    const float* x      = (const float*)d_in[0];
    const float* q      = (const float*)d_in[1];
    const float* keys   = (const float*)d_in[2];
    const float* Wu     = (const float*)d_in[3];
    const float* bu     = (const float*)d_in[4];
    const int*   lens   = (const int*)d_in[5];
    const int*   labels = (const int*)d_in[6];
    const int*   qlab   = (const int*)d_in[7];
    float* out = (float*)d_out;

    hipLaunchKernelGGL(mem_net_kernel, dim3(NB), dim3(256), 0, stream,
                       x, q, keys, Wu, bu, lens, labels, qlab, out);
}